// Round 10
// baseline (559.447 us; speedup 1.0000x reference)
//
#include <hip/hip_runtime.h>

#define B_ 64
#define T_ 2000
#define V_ 512
#define L_ 200
#define NJB 63   // j-blocks per batch in kprob: 63*4 waves = 252 >= max nch (250)
#define NCH 250  // max chunks per batch

// Two-phase CTC, zero inter-block sync. krec was ~150us (~2900 cy/chunk vs
// ~170 cy compute) -> exposed memory latency. Fixes:
//  - compact stream packed 16B/lane (2 timesteps per u64x2): 6 loads/chunk
//  - krec pipeline deepened to 6 chunks (36 loads in flight), named buffers,
//    compile-time indexing -> compiler can emit precise rotating vmcnt
//  - kprob stores non-temporal: lands in L3/HBM, not dirty in a foreign XCD L2
// Round-9 compile fixes: ext_vector_type for nontemporal stores; letter-
// suffixed pipeline buffer names (Qa##S) to avoid the '2.x' pp-number paste.

typedef _Float16 half4 __attribute__((ext_vector_type(4)));
typedef unsigned long long ull;
typedef ull u64x2 __attribute__((ext_vector_type(2)));
typedef float f32x4 __attribute__((ext_vector_type(4)));
union H4U { unsigned long long u; half4 h; };

__device__ __forceinline__ float dpp_shr1_f(float x) {  // lane i <- lane i-1; lane0 <- 0
  return __int_as_float(__builtin_amdgcn_update_dpp(0, __float_as_int(x), 0x138, 0xf, 0xf, true));
}
__device__ __forceinline__ int dpp_shr1_i(int x) {
  return __builtin_amdgcn_update_dpp(0, x, 0x138, 0xf, 0xf, true);
}
__device__ __forceinline__ float dpp_shl1_f(float x) {  // lane i <- lane i+1; lane63 <- 0
  return __int_as_float(__builtin_amdgcn_update_dpp(0, __float_as_int(x), 0x130, 0xf, 0xf, true));
}
__device__ __forceinline__ int dpp_shl1_i(int x) {
  return __builtin_amdgcn_update_dpp(0, x, 0x130, 0xf, 0xf, true);
}
#define DPPADD(v, ctrl, rmask)                                                              \
  v += __int_as_float(__builtin_amdgcn_update_dpp(0, __float_as_int(v), ctrl, rmask, 0xf, true));

#define COMPACT(BB)                                                          \
  int base = 0;                                                              \
  {                                                                          \
    cmp[lane] = 0; cmp[64 + lane] = 0; cmp[128 + lane] = 0; cmp[192 + lane] = 0; \
    _Pragma("unroll") for (int cc = 0; cc < 4; ++cc) {                       \
      const int l = cc * 64 + lane;                                          \
      const int v = (l < L_) ? targets[(BB) * L_ + l] : 0;                   \
      const unsigned long long mk = __ballot(v != 0);                        \
      const int pos = base + __popcll(mk & ((1ull << lane) - 1ull));         \
      if (v != 0) cmp[pos] = v;                                              \
      base += __popcll(mk);                                                  \
    }                                                                        \
    asm volatile("s_waitcnt lgkmcnt(0)" ::: "memory");                       \
  }

// ================== phase A: softmax + gather -> compact fp16 ==================
__global__ __launch_bounds__(256, 4) void kprob(const float* __restrict__ logits,
                                                const int* __restrict__ lens,
                                                const int* __restrict__ targets,
                                                u64x2* __restrict__ cull2,
                                                float* __restrict__ bl) {
  const int tid = threadIdx.x;
  const int wid = tid >> 6;
  const int lane = tid & 63;
  __shared__ int cmp[256];
  __shared__ __align__(16) float scr[4][2][512];  // per-wave exp scratch

  const int g = blockIdx.x;
  const int b = g & 63;
  const int jb = g >> 6;
  const int len = lens[b];
  const int nch = (len + 7) >> 3;
  if (wid == 0) { COMPACT(b); }
  __syncthreads();
  const int c = jb * 4 + wid;  // this wave's 8-step chunk
  if (c >= nch) return;

  const int4 c4 = *(const int4*)(&cmp[4 * lane]);
  const int l0 = 4 * lane;
  const bool v0 = l0 + 0 < L_, v1 = l0 + 1 < L_, v2 = l0 + 2 < L_, v3 = l0 + 3 < L_;

  const float* rowp = logits + (size_t)b * (T_ * V_) + (size_t)c * (8 * V_);
  float4 X[16];
#pragma unroll
  for (int r = 0; r < 8; ++r) {  // issue all row loads up front
    X[2 * r] = *(const float4*)(rowp + r * V_ + 4 * lane);
    X[2 * r + 1] = *(const float4*)(rowp + r * V_ + 256 + 4 * lane);
  }
  u64x2* outp = cull2 + ((size_t)(b * NCH + c) * 4) * 64 + lane;
  unsigned long long pe = 0;
  float blb0 = 0, blb1 = 0, blb2 = 0, blb3 = 0, blb4 = 0, blb5 = 0, blb6 = 0, blb7 = 0;
#pragma unroll
  for (int r = 0; r < 8; ++r) {
    const float4 xe = X[2 * r], xo = X[2 * r + 1];
    const float e0 = __expf(xe.x), e1 = __expf(xe.y), e2 = __expf(xe.z), e3 = __expf(xe.w);
    const float e4 = __expf(xo.x), e5 = __expf(xo.y), e6 = __expf(xo.z), e7 = __expf(xo.w);
    float s = ((e0 + e1) + (e2 + e3)) + ((e4 + e5) + (e6 + e7));
    DPPADD(s, 0x111, 0xf); DPPADD(s, 0x112, 0xf); DPPADD(s, 0x114, 0xf);
    DPPADD(s, 0x118, 0xf); DPPADD(s, 0x142, 0xa); DPPADD(s, 0x143, 0xc);
    const float sum = __int_as_float(__builtin_amdgcn_readlane(__float_as_int(s), 63));
    const float inv = 32.0f / sum;  // same x32 prescale as verified kernels
    float* sc = &scr[wid][r & 1][0];  // 2-slot alternation; wave-ordered LDS pipe
    *(float4*)(sc + 4 * lane) = make_float4(e0, e1, e2, e3);
    *(float4*)(sc + 256 + 4 * lane) = make_float4(e4, e5, e6, e7);
    asm volatile("s_waitcnt lgkmcnt(0)" ::: "memory");
    H4U p;
    p.h.x = (_Float16)(v0 ? sc[c4.x] * inv : 0.0f);  // LDS gather, conflict-cheap
    p.h.y = (_Float16)(v1 ? sc[c4.y] * inv : 0.0f);
    p.h.z = (_Float16)(v2 ? sc[c4.z] * inv : 0.0f);
    p.h.w = (_Float16)(v3 ? sc[c4.w] * inv : 0.0f);
    if (r & 1) {  // pack two timesteps per 16B, non-temporal store
      u64x2 w; w.x = pe; w.y = p.u;
      __builtin_nontemporal_store(w, outp + (r >> 1) * 64);
    } else {
      pe = p.u;
    }
    const float bv = e0 * inv;  // blank prob (class 0)
    switch (r) {
      case 0: blb0 = bv; break; case 1: blb1 = bv; break;
      case 2: blb2 = bv; break; case 3: blb3 = bv; break;
      case 4: blb4 = bv; break; case 5: blb5 = bv; break;
      case 6: blb6 = bv; break; default: blb7 = bv; break;
    }
  }
  if (lane == 0) {
    f32x4* bp = (f32x4*)(bl + b * 2048 + c * 8);
    f32x4 w0 = {blb0, blb1, blb2, blb3};
    f32x4 w1 = {blb4, blb5, blb6, blb7};
    __builtin_nontemporal_store(w0, bp);
    __builtin_nontemporal_store(w1, bp + 1);
  }
}

// ================== phase B: fwd/bwd block-float recursions ==================
__global__ __launch_bounds__(64) void krec(const int* __restrict__ lens,
                                           const int* __restrict__ targets,
                                           const u64x2* __restrict__ cull2,
                                           const float* __restrict__ bl,
                                           float* __restrict__ AF, int* __restrict__ EF,
                                           float* __restrict__ DD, int* __restrict__ EB) {
  const int lane = threadIdx.x;
  __shared__ int cmp[256];
  const int b = blockIdx.x >> 1;
  const int dirb = blockIdx.x & 1;
  const int len = lens[b];
  const int rem = len & 7;
  const int nch = (len + 7) >> 3;
  const int Cf = nch >> 1;  // fwd owns chunks [0, Cf) (all full); bwd owns [Cf, nch)
  const int Ntot = dirb ? (nch - Cf) : Cf;  // >= 109 always (len >= 1744)
  const int c0v = dirb ? (nch - 1) : 0;
  const int dstep = dirb ? -1 : 1;
#define CHK(J) (c0v + dstep * (J))

  COMPACT(b);
  const int tl = base;
  const int4 c4 = *(const int4*)(&cmp[4 * lane]);

  const int cm1 = __shfl_up(c4.w, 1);
  const float m0 = (lane > 0 && c4.x != 0 && c4.x != cm1) ? 1.0f : 0.0f;
  const float m1 = (c4.y != 0 && c4.y != c4.x) ? 1.0f : 0.0f;
  const float m2 = (c4.z != 0 && c4.z != c4.y) ? 1.0f : 0.0f;
  const float m3 = (c4.w != 0 && c4.w != c4.z) ? 1.0f : 0.0f;
  const float m0n = dpp_shl1_f(m0);

  float a0 = 0.f, a1 = 0.f, a2 = 0.f, a3 = 0.f, a4 = 0.f, a5 = 0.f, a6 = 0.f, a7 = 0.f;
  int E = 0;
  float fac = 1.0f;
  if (!dirb) {
    if (lane == 0) a0 = 1.0f;  // chunk-0 step u=0 reproduces the alpha init
  } else {
    const int st = 2 * tl;  // gamma seed; first bwd step reproduces the init
    if (lane == (st >> 3)) {
      const int e = st & 7;
      a0 = (e == 0) ? 1.0f : 0.0f; a1 = (e == 1) ? 1.0f : 0.0f;
      a2 = (e == 2) ? 1.0f : 0.0f; a3 = (e == 3) ? 1.0f : 0.0f;
      a4 = (e == 4) ? 1.0f : 0.0f; a5 = (e == 5) ? 1.0f : 0.0f;
      a6 = (e == 6) ? 1.0f : 0.0f; a7 = (e == 7) ? 1.0f : 0.0f;
    }
  }

  // 6-deep pipeline buffers (named; all indexing compile-time)
  u64x2 Qa0, Qb0, Qc0, Qd0, Qa1, Qb1, Qc1, Qd1, Qa2, Qb2, Qc2, Qd2;
  u64x2 Qa3, Qb3, Qc3, Qd3, Qa4, Qb4, Qc4, Qd4, Qa5, Qb5, Qc5, Qd5;
  float4 BLa0, BLb0, BLa1, BLb1, BLa2, BLb2, BLa3, BLb3, BLa4, BLb4, BLa5, BLb5;

#define LOADC(S, CIDX)                                                       \
  {                                                                          \
    const int c_ = (CIDX);                                                   \
    const u64x2* pp_ = cull2 + ((size_t)(b * NCH + c_) * 4) * 64 + lane;     \
    Qa##S = pp_[0]; Qb##S = pp_[64]; Qc##S = pp_[128]; Qd##S = pp_[192];     \
    const float* bf_ = bl + b * 2048 + c_ * 8;                               \
    BLa##S = *(const float4*)(bf_);                                          \
    BLb##S = *(const float4*)(bf_ + 4);                                      \
  }

#define STEP8F(S)                                                            \
  {                                                                          \
    const float blv_[8] = {BLa##S.x, BLa##S.y, BLa##S.z, BLa##S.w,           \
                           BLb##S.x, BLb##S.y, BLb##S.z, BLb##S.w};          \
    const unsigned long long qu_[8] = {Qa##S.x, Qa##S.y, Qb##S.x, Qb##S.y,   \
                                       Qc##S.x, Qc##S.y, Qd##S.x, Qd##S.y};  \
    _Pragma("unroll") for (int u = 0; u < 8; ++u) {                          \
      H4U q_; q_.u = qu_[u];                                                 \
      const float qx = (float)q_.h.x, qy = (float)q_.h.y;                    \
      const float qz = (float)q_.h.z, qw = (float)q_.h.w;                    \
      const float pbv = blv_[u];                                             \
      const float s1 = dpp_shr1_f(a7) * fac;  /* lane0 -> 0 */               \
      float n0 = (a0 + s1) * pbv;                                            \
      float n1 = fmaf(m0, s1, a0 + a1) * qx;                                 \
      float n2 = (a2 + a1) * pbv;                                            \
      float n3 = fmaf(m1, a1, a2 + a3) * qy;                                 \
      float n4 = (a4 + a3) * pbv;                                            \
      float n5 = fmaf(m2, a3, a4 + a5) * qz;                                 \
      float n6 = (a6 + a5) * pbv;                                            \
      float n7 = fmaf(m3, a5, a6 + a7) * qw;                                 \
      a0 = n0; a1 = n1; a2 = n2; a3 = n3;                                    \
      a4 = n4; a5 = n5; a6 = n6; a7 = n7;                                    \
    }                                                                        \
  }

#define STEP8B(S, UHI)                                                       \
  {                                                                          \
    const float blv_[8] = {BLa##S.x, BLa##S.y, BLa##S.z, BLa##S.w,           \
                           BLb##S.x, BLb##S.y, BLb##S.z, BLb##S.w};          \
    const unsigned long long qu_[8] = {Qa##S.x, Qa##S.y, Qb##S.x, Qb##S.y,   \
                                       Qc##S.x, Qc##S.y, Qd##S.x, Qd##S.y};  \
    _Pragma("unroll") for (int u = 7; u >= 0; --u) {                         \
      if (u <= (UHI)) {                                                      \
        H4U q_; q_.u = qu_[u];                                               \
        const float qx = (float)q_.h.x, qy = (float)q_.h.y;                  \
        const float qz = (float)q_.h.z, qw = (float)q_.h.w;                  \
        const float pbv = blv_[u];                                           \
        const float sa = dpp_shl1_f(a0) * fac;  /* lane63 -> 0 */            \
        const float sb = dpp_shl1_f(a1) * fac;                               \
        float n0 = (a0 + a1) * pbv;                                          \
        float n1 = fmaf(m1, a3, a1 + a2) * qx;                               \
        float n2 = (a2 + a3) * pbv;                                          \
        float n3 = fmaf(m2, a5, a3 + a4) * qy;                               \
        float n4 = (a4 + a5) * pbv;                                          \
        float n5 = fmaf(m3, a7, a5 + a6) * qz;                               \
        float n6 = (a6 + a7) * pbv;                                          \
        float n7 = fmaf(m0n, sb, a7 + sa) * qw;                              \
        a0 = n0; a1 = n1; a2 = n2; a3 = n3;                                  \
        a4 = n4; a5 = n5; a6 = n6; a7 = n7;                                  \
      }                                                                      \
    }                                                                        \
  }

#define RENORM_COMMON                                                        \
    const float mx = fmaxf(fmaxf(fmaxf(a0, a1), fmaxf(a2, a3)),              \
                           fmaxf(fmaxf(a4, a5), fmaxf(a6, a7)));             \
    const bool dead = (mx == 0.0f);                                          \
    int e_ = (int)((__float_as_uint(mx) >> 23) & 0xff) - 127;                \
    if (dead) e_ = 0;                                                        \
    const float sc_ = __int_as_float((unsigned)(127 - e_) << 23);            \
    a0 *= sc_; a1 *= sc_; a2 *= sc_; a3 *= sc_;                              \
    a4 *= sc_; a5 *= sc_; a6 *= sc_; a7 *= sc_;                              \
    const int En_ = E + e_;

#define RENORMF                                                              \
  {                                                                          \
    RENORM_COMMON                                                            \
    const int EnP_ = dpp_shr1_i(En_);                                        \
    E = dead ? EnP_ : En_;                                                   \
    const int Ep_ = dpp_shr1_i(E);                                           \
    const int d_ = Ep_ - E;                                                  \
    int dc_ = d_ < -126 ? -126 : (d_ > 126 ? 126 : d_);                      \
    fac = (d_ < -126) ? 0.0f : __int_as_float((unsigned)(dc_ + 127) << 23);  \
  }

#define RENORMB                                                              \
  {                                                                          \
    RENORM_COMMON                                                            \
    const int EnP_ = dpp_shl1_i(En_);                                        \
    E = dead ? EnP_ : En_;                                                   \
    const int Ep_ = dpp_shl1_i(E);                                           \
    const int d_ = Ep_ - E;                                                  \
    int dc_ = d_ < -126 ? -126 : (d_ > 126 ? 126 : d_);                      \
    fac = (d_ < -126) ? 0.0f : __int_as_float((unsigned)(dc_ + 127) << 23);  \
  }

  // prologue: 6-chunk register prefetch (Ntot >= 109 always)
  LOADC(0, CHK(0)); LOADC(1, CHK(1)); LOADC(2, CHK(2));
  LOADC(3, CHK(3)); LOADC(4, CHK(4)); LOADC(5, CHK(5));

  if (!dirb) {
    int ph = 0;
    for (int i = 0; i < Ntot; ++i) {
      const int nx = i + 6;
      const bool pf = nx < Ntot;
      switch (ph) {
        case 0: STEP8F(0); RENORMF; if (pf) LOADC(0, CHK(nx)); break;
        case 1: STEP8F(1); RENORMF; if (pf) LOADC(1, CHK(nx)); break;
        case 2: STEP8F(2); RENORMF; if (pf) LOADC(2, CHK(nx)); break;
        case 3: STEP8F(3); RENORMF; if (pf) LOADC(3, CHK(nx)); break;
        case 4: STEP8F(4); RENORMF; if (pf) LOADC(4, CHK(nx)); break;
        default: STEP8F(5); RENORMF; if (pf) LOADC(5, CHK(nx)); break;
      }
      ph = (ph == 5) ? 0 : ph + 1;
    }
    *(float4*)(AF + b * 512 + lane * 8) = make_float4(a0, a1, a2, a3);
    *(float4*)(AF + b * 512 + lane * 8 + 4) = make_float4(a4, a5, a6, a7);
    EF[b * 64 + lane] = E;
  } else {
    int ph = 0;
    for (int i = 0; i < Ntot; ++i) {
      const int nx = i + 6;
      const bool pf = nx < Ntot;
      const int uh = (i == 0 && rem) ? (rem - 1) : 7;  // masked tail consumed first
      switch (ph) {
        case 0: STEP8B(0, uh); RENORMB; if (pf) LOADC(0, CHK(nx)); break;
        case 1: STEP8B(1, uh); RENORMB; if (pf) LOADC(1, CHK(nx)); break;
        case 2: STEP8B(2, uh); RENORMB; if (pf) LOADC(2, CHK(nx)); break;
        case 3: STEP8B(3, uh); RENORMB; if (pf) LOADC(3, CHK(nx)); break;
        case 4: STEP8B(4, uh); RENORMB; if (pf) LOADC(4, CHK(nx)); break;
        default: STEP8B(5, uh); RENORMB; if (pf) LOADC(5, CHK(nx)); break;
      }
      ph = (ph == 5) ? 0 : ph + 1;
    }
    // delta = one emission-less backward step of gamma_{8Cf}
    const float sa = dpp_shl1_f(a0) * fac;
    const float sb = dpp_shl1_f(a1) * fac;
    const float d0 = a0 + a1;
    const float d1 = fmaf(m1, a3, a1 + a2);
    const float d2 = a2 + a3;
    const float d3 = fmaf(m2, a5, a3 + a4);
    const float d4 = a4 + a5;
    const float d5 = fmaf(m3, a7, a5 + a6);
    const float d6 = a6 + a7;
    const float d7 = fmaf(m0n, sb, a7 + sa);
    *(float4*)(DD + b * 512 + lane * 8) = make_float4(d0, d1, d2, d3);
    *(float4*)(DD + b * 512 + lane * 8 + 4) = make_float4(d4, d5, d6, d7);
    EB[b * 64 + lane] = E;
  }
#undef LOADC
#undef STEP8F
#undef STEP8B
#undef RENORM_COMMON
#undef RENORMF
#undef RENORMB
#undef CHK
}

// ---- splice + final sum: out = -sum_b log( sum_s alpha[s]*delta[s] ) + len*ln(32) ----
__global__ __launch_bounds__(512) void kcomb(const int* __restrict__ lens,
                                             const float* __restrict__ AF,
                                             const int* __restrict__ EF,
                                             const float* __restrict__ DD,
                                             const int* __restrict__ EB,
                                             float* __restrict__ out) {
  const int wid = threadIdx.x >> 6;
  const int lane = threadIdx.x & 63;
  __shared__ float part[8];
  float acc = 0.0f;
#pragma unroll
  for (int q = 0; q < 8; ++q) {
    const int b = wid * 8 + q;
    const float4 f0 = *(const float4*)(AF + b * 512 + lane * 8);
    const float4 f1 = *(const float4*)(AF + b * 512 + lane * 8 + 4);
    const float4 g0 = *(const float4*)(DD + b * 512 + lane * 8);
    const float4 g1 = *(const float4*)(DD + b * 512 + lane * 8 + 4);
    const float dot = ((f0.x * g0.x + f0.y * g0.y) + (f0.z * g0.z + f0.w * g0.w)) +
                      ((f1.x * g1.x + f1.y * g1.y) + (f1.z * g1.z + f1.w * g1.w));
    const int Es = EF[b * 64 + lane] + EB[b * 64 + lane];
    const bool z = (dot == 0.0f);
    int Ek = z ? (-(1 << 28)) : Es;
#pragma unroll
    for (int off = 32; off; off >>= 1) {
      const int o = __shfl_xor(Ek, off);
      Ek = o > Ek ? o : Ek;
    }
    float v = z ? 0.0f : ldexpf(dot, Es - Ek);
#pragma unroll
    for (int off = 32; off; off >>= 1) v += __shfl_xor(v, off);
    const float ll = __logf(v) + (float)Ek * 0.69314718056f - (float)lens[b] * 3.46573590280f;
    acc -= ll;
  }
  if (lane == 0) part[wid] = acc;
  __syncthreads();
  if (threadIdx.x == 0) {
    float s = ((part[0] + part[1]) + (part[2] + part[3])) +
              ((part[4] + part[5]) + (part[6] + part[7]));
    out[0] = s;
  }
}

extern "C" void kernel_launch(void* const* d_in, const int* in_sizes, int n_in,
                              void* d_out, int out_size, void* d_ws, size_t ws_size,
                              hipStream_t stream) {
  const float* logits = (const float*)d_in[0];     // [B,T,V] fp32 — read-only
  const int* input_lengths = (const int*)d_in[1];  // [B]
  const int* targets = (const int*)d_in[2];        // [B,L]
  float* out = (float*)d_out;                      // [1]
  // ws layout (bytes): compact fp16 pairs [B][250][4][64] x16B = 65,536,000;
  // blank f32 [B][2048] = 524,288; (gap); AF/EF/DD/EB.
  u64x2* cull2 = (u64x2*)d_ws;
  float* bl = (float*)((char*)d_ws + 65536000);
  float* AF = (float*)((char*)d_ws + 66125824);
  int* EF = (int*)((char*)d_ws + 66256896);
  float* DD = (float*)((char*)d_ws + 66273280);
  int* EB = (int*)((char*)d_ws + 66404352);
  (void)in_sizes; (void)n_in; (void)out_size; (void)ws_size;

  kprob<<<B_ * NJB, 256, 0, stream>>>(logits, input_lengths, targets, cull2, bl);
  krec<<<2 * B_, 64, 0, stream>>>(input_lengths, targets, cull2, bl, AF, EF, DD, EB);
  kcomb<<<1, 512, 0, stream>>>(input_lengths, AF, EF, DD, EB, out);
}

// Round 11
// 435.475 us; speedup vs baseline: 1.2847x; 1.2847x over previous
//
#include <hip/hip_runtime.h>

#define B_ 64
#define T_ 2000
#define V_ 512
#define L_ 200
#define NJB 63   // j-blocks per batch in kprob: 63*4 waves = 252 >= max nch (250)
#define NCH 250  // max chunks per batch

// Two-phase CTC, zero inter-block sync. Round-10 post-mortem: switch-based
// buffer rotation defeated the software pipeline (compiler emitted
// conservative vmcnt at block merges -> <1 chunk in flight, 161 GB/s), and
// non-temporal stores evicted the compact stream from L3 (krec FETCH=31MB of
// pure HBM misses). Fixes:
//  - krec main loop is STRAIGHT-LINE 6-chunk groups (peeled first group for
//    the bwd masked tail; switch-based drain only for the last <12 chunks)
//    so the compiler can emit counted rotating vmcnt -> ~30 loads in flight
//  - kprob stores reverted to plain L2-cached (end-of-kernel writeback
//    leaves the 66MB stream L3-resident for krec)
// Arithmetic bit-identical to the round-8/10-verified versions.

typedef _Float16 half4 __attribute__((ext_vector_type(4)));
typedef unsigned long long ull;
typedef ull u64x2 __attribute__((ext_vector_type(2)));
union H4U { unsigned long long u; half4 h; };

__device__ __forceinline__ float dpp_shr1_f(float x) {  // lane i <- lane i-1; lane0 <- 0
  return __int_as_float(__builtin_amdgcn_update_dpp(0, __float_as_int(x), 0x138, 0xf, 0xf, true));
}
__device__ __forceinline__ int dpp_shr1_i(int x) {
  return __builtin_amdgcn_update_dpp(0, x, 0x138, 0xf, 0xf, true);
}
__device__ __forceinline__ float dpp_shl1_f(float x) {  // lane i <- lane i+1; lane63 <- 0
  return __int_as_float(__builtin_amdgcn_update_dpp(0, __float_as_int(x), 0x130, 0xf, 0xf, true));
}
__device__ __forceinline__ int dpp_shl1_i(int x) {
  return __builtin_amdgcn_update_dpp(0, x, 0x130, 0xf, 0xf, true);
}
#define DPPADD(v, ctrl, rmask)                                                              \
  v += __int_as_float(__builtin_amdgcn_update_dpp(0, __float_as_int(v), ctrl, rmask, 0xf, true));

#define COMPACT(BB)                                                          \
  int base = 0;                                                              \
  {                                                                          \
    cmp[lane] = 0; cmp[64 + lane] = 0; cmp[128 + lane] = 0; cmp[192 + lane] = 0; \
    _Pragma("unroll") for (int cc = 0; cc < 4; ++cc) {                       \
      const int l = cc * 64 + lane;                                          \
      const int v = (l < L_) ? targets[(BB) * L_ + l] : 0;                   \
      const unsigned long long mk = __ballot(v != 0);                        \
      const int pos = base + __popcll(mk & ((1ull << lane) - 1ull));         \
      if (v != 0) cmp[pos] = v;                                              \
      base += __popcll(mk);                                                  \
    }                                                                        \
    asm volatile("s_waitcnt lgkmcnt(0)" ::: "memory");                       \
  }

// ================== phase A: softmax + gather -> compact fp16 ==================
__global__ __launch_bounds__(256, 4) void kprob(const float* __restrict__ logits,
                                                const int* __restrict__ lens,
                                                const int* __restrict__ targets,
                                                u64x2* __restrict__ cull2,
                                                float* __restrict__ bl) {
  const int tid = threadIdx.x;
  const int wid = tid >> 6;
  const int lane = tid & 63;
  __shared__ int cmp[256];
  __shared__ __align__(16) float scr[4][2][512];  // per-wave exp scratch

  const int g = blockIdx.x;
  const int b = g & 63;
  const int jb = g >> 6;
  const int len = lens[b];
  const int nch = (len + 7) >> 3;
  if (wid == 0) { COMPACT(b); }
  __syncthreads();
  const int c = jb * 4 + wid;  // this wave's 8-step chunk
  if (c >= nch) return;

  const int4 c4 = *(const int4*)(&cmp[4 * lane]);
  const int l0 = 4 * lane;
  const bool v0 = l0 + 0 < L_, v1 = l0 + 1 < L_, v2 = l0 + 2 < L_, v3 = l0 + 3 < L_;

  const float* rowp = logits + (size_t)b * (T_ * V_) + (size_t)c * (8 * V_);
  float4 X[16];
#pragma unroll
  for (int r = 0; r < 8; ++r) {  // issue all row loads up front
    X[2 * r] = *(const float4*)(rowp + r * V_ + 4 * lane);
    X[2 * r + 1] = *(const float4*)(rowp + r * V_ + 256 + 4 * lane);
  }
  u64x2* outp = cull2 + ((size_t)(b * NCH + c) * 4) * 64 + lane;
  unsigned long long pe = 0;
  float blb[8];
#pragma unroll
  for (int r = 0; r < 8; ++r) {
    const float4 xe = X[2 * r], xo = X[2 * r + 1];
    const float e0 = __expf(xe.x), e1 = __expf(xe.y), e2 = __expf(xe.z), e3 = __expf(xe.w);
    const float e4 = __expf(xo.x), e5 = __expf(xo.y), e6 = __expf(xo.z), e7 = __expf(xo.w);
    float s = ((e0 + e1) + (e2 + e3)) + ((e4 + e5) + (e6 + e7));
    DPPADD(s, 0x111, 0xf); DPPADD(s, 0x112, 0xf); DPPADD(s, 0x114, 0xf);
    DPPADD(s, 0x118, 0xf); DPPADD(s, 0x142, 0xa); DPPADD(s, 0x143, 0xc);
    const float sum = __int_as_float(__builtin_amdgcn_readlane(__float_as_int(s), 63));
    const float inv = 32.0f / sum;  // same x32 prescale as verified kernels
    float* sc = &scr[wid][r & 1][0];  // 2-slot alternation; wave-ordered LDS pipe
    *(float4*)(sc + 4 * lane) = make_float4(e0, e1, e2, e3);
    *(float4*)(sc + 256 + 4 * lane) = make_float4(e4, e5, e6, e7);
    asm volatile("s_waitcnt lgkmcnt(0)" ::: "memory");
    H4U p;
    p.h.x = (_Float16)(v0 ? sc[c4.x] * inv : 0.0f);  // LDS gather, conflict-cheap
    p.h.y = (_Float16)(v1 ? sc[c4.y] * inv : 0.0f);
    p.h.z = (_Float16)(v2 ? sc[c4.z] * inv : 0.0f);
    p.h.w = (_Float16)(v3 ? sc[c4.w] * inv : 0.0f);
    if (r & 1) {  // pack two timesteps per 16B, plain L2-cached store
      u64x2 w; w.x = pe; w.y = p.u;
      outp[(r >> 1) * 64] = w;
    } else {
      pe = p.u;
    }
    blb[r] = e0 * inv;  // blank prob (class 0)
  }
  if (lane == 0) {
    float4* bp = (float4*)(bl + b * 2048 + c * 8);
    bp[0] = make_float4(blb[0], blb[1], blb[2], blb[3]);
    bp[1] = make_float4(blb[4], blb[5], blb[6], blb[7]);
  }
}

// ================== phase B: fwd/bwd block-float recursions ==================
__global__ __launch_bounds__(64) void krec(const int* __restrict__ lens,
                                           const int* __restrict__ targets,
                                           const u64x2* __restrict__ cull2,
                                           const float* __restrict__ bl,
                                           float* __restrict__ AF, int* __restrict__ EF,
                                           float* __restrict__ DD, int* __restrict__ EB) {
  const int lane = threadIdx.x;
  __shared__ int cmp[256];
  const int b = blockIdx.x >> 1;
  const int dirb = blockIdx.x & 1;
  const int len = lens[b];
  const int rem = len & 7;
  const int nch = (len + 7) >> 3;
  const int Cf = nch >> 1;  // fwd owns chunks [0, Cf) (all full); bwd owns [Cf, nch)
  const int Ntot = dirb ? (nch - Cf) : Cf;  // in [109,125] (len >= 1744)
  const int c0v = dirb ? (nch - 1) : 0;
  const int dstep = dirb ? -1 : 1;
#define CHK(J) (c0v + dstep * (J))

  COMPACT(b);
  const int tl = base;
  const int4 c4 = *(const int4*)(&cmp[4 * lane]);

  const int cm1 = __shfl_up(c4.w, 1);
  const float m0 = (lane > 0 && c4.x != 0 && c4.x != cm1) ? 1.0f : 0.0f;
  const float m1 = (c4.y != 0 && c4.y != c4.x) ? 1.0f : 0.0f;
  const float m2 = (c4.z != 0 && c4.z != c4.y) ? 1.0f : 0.0f;
  const float m3 = (c4.w != 0 && c4.w != c4.z) ? 1.0f : 0.0f;
  const float m0n = dpp_shl1_f(m0);

  float a0 = 0.f, a1 = 0.f, a2 = 0.f, a3 = 0.f, a4 = 0.f, a5 = 0.f, a6 = 0.f, a7 = 0.f;
  int E = 0;
  float fac = 1.0f;
  if (!dirb) {
    if (lane == 0) a0 = 1.0f;  // chunk-0 step u=0 reproduces the alpha init
  } else {
    const int st = 2 * tl;  // gamma seed; first bwd step reproduces the init
    if (lane == (st >> 3)) {
      const int e = st & 7;
      a0 = (e == 0) ? 1.0f : 0.0f; a1 = (e == 1) ? 1.0f : 0.0f;
      a2 = (e == 2) ? 1.0f : 0.0f; a3 = (e == 3) ? 1.0f : 0.0f;
      a4 = (e == 4) ? 1.0f : 0.0f; a5 = (e == 5) ? 1.0f : 0.0f;
      a6 = (e == 6) ? 1.0f : 0.0f; a7 = (e == 7) ? 1.0f : 0.0f;
    }
  }

  // 6-deep pipeline buffers (named; all indexing compile-time)
  u64x2 Qa0, Qb0, Qc0, Qd0, Qa1, Qb1, Qc1, Qd1, Qa2, Qb2, Qc2, Qd2;
  u64x2 Qa3, Qb3, Qc3, Qd3, Qa4, Qb4, Qc4, Qd4, Qa5, Qb5, Qc5, Qd5;
  float4 BLa0, BLb0, BLa1, BLb1, BLa2, BLb2, BLa3, BLb3, BLa4, BLb4, BLa5, BLb5;

#define LOADC(S, CIDX)                                                       \
  {                                                                          \
    const int c_ = (CIDX);                                                   \
    const u64x2* pp_ = cull2 + ((size_t)(b * NCH + c_) * 4) * 64 + lane;     \
    Qa##S = pp_[0]; Qb##S = pp_[64]; Qc##S = pp_[128]; Qd##S = pp_[192];     \
    const float* bf_ = bl + b * 2048 + c_ * 8;                               \
    BLa##S = *(const float4*)(bf_);                                          \
    BLb##S = *(const float4*)(bf_ + 4);                                      \
  }

#define STEP8F(S)                                                            \
  {                                                                          \
    const float blv_[8] = {BLa##S.x, BLa##S.y, BLa##S.z, BLa##S.w,           \
                           BLb##S.x, BLb##S.y, BLb##S.z, BLb##S.w};          \
    const unsigned long long qu_[8] = {Qa##S.x, Qa##S.y, Qb##S.x, Qb##S.y,   \
                                       Qc##S.x, Qc##S.y, Qd##S.x, Qd##S.y};  \
    _Pragma("unroll") for (int u = 0; u < 8; ++u) {                          \
      H4U q_; q_.u = qu_[u];                                                 \
      const float qx = (float)q_.h.x, qy = (float)q_.h.y;                    \
      const float qz = (float)q_.h.z, qw = (float)q_.h.w;                    \
      const float pbv = blv_[u];                                             \
      const float s1 = dpp_shr1_f(a7) * fac;  /* lane0 -> 0 */               \
      float n0 = (a0 + s1) * pbv;                                            \
      float n1 = fmaf(m0, s1, a0 + a1) * qx;                                 \
      float n2 = (a2 + a1) * pbv;                                            \
      float n3 = fmaf(m1, a1, a2 + a3) * qy;                                 \
      float n4 = (a4 + a3) * pbv;                                            \
      float n5 = fmaf(m2, a3, a4 + a5) * qz;                                 \
      float n6 = (a6 + a5) * pbv;                                            \
      float n7 = fmaf(m3, a5, a6 + a7) * qw;                                 \
      a0 = n0; a1 = n1; a2 = n2; a3 = n3;                                    \
      a4 = n4; a5 = n5; a6 = n6; a7 = n7;                                    \
    }                                                                        \
  }

#define STEP8B(S, UHI)                                                       \
  {                                                                          \
    const float blv_[8] = {BLa##S.x, BLa##S.y, BLa##S.z, BLa##S.w,           \
                           BLb##S.x, BLb##S.y, BLb##S.z, BLb##S.w};          \
    const unsigned long long qu_[8] = {Qa##S.x, Qa##S.y, Qb##S.x, Qb##S.y,   \
                                       Qc##S.x, Qc##S.y, Qd##S.x, Qd##S.y};  \
    _Pragma("unroll") for (int u = 7; u >= 0; --u) {                         \
      if (u <= (UHI)) {                                                      \
        H4U q_; q_.u = qu_[u];                                               \
        const float qx = (float)q_.h.x, qy = (float)q_.h.y;                  \
        const float qz = (float)q_.h.z, qw = (float)q_.h.w;                  \
        const float pbv = blv_[u];                                           \
        const float sa = dpp_shl1_f(a0) * fac;  /* lane63 -> 0 */            \
        const float sb = dpp_shl1_f(a1) * fac;                               \
        float n0 = (a0 + a1) * pbv;                                          \
        float n1 = fmaf(m1, a3, a1 + a2) * qx;                               \
        float n2 = (a2 + a3) * pbv;                                          \
        float n3 = fmaf(m2, a5, a3 + a4) * qy;                               \
        float n4 = (a4 + a5) * pbv;                                          \
        float n5 = fmaf(m3, a7, a5 + a6) * qz;                               \
        float n6 = (a6 + a7) * pbv;                                          \
        float n7 = fmaf(m0n, sb, a7 + sa) * qw;                              \
        a0 = n0; a1 = n1; a2 = n2; a3 = n3;                                  \
        a4 = n4; a5 = n5; a6 = n6; a7 = n7;                                  \
      }                                                                      \
    }                                                                        \
  }

#define RENORM_COMMON                                                        \
    const float mx = fmaxf(fmaxf(fmaxf(a0, a1), fmaxf(a2, a3)),              \
                           fmaxf(fmaxf(a4, a5), fmaxf(a6, a7)));             \
    const bool dead = (mx == 0.0f);                                          \
    int e_ = (int)((__float_as_uint(mx) >> 23) & 0xff) - 127;                \
    if (dead) e_ = 0;                                                        \
    const float sc_ = __int_as_float((unsigned)(127 - e_) << 23);            \
    a0 *= sc_; a1 *= sc_; a2 *= sc_; a3 *= sc_;                              \
    a4 *= sc_; a5 *= sc_; a6 *= sc_; a7 *= sc_;                              \
    const int En_ = E + e_;

#define RENORMF                                                              \
  {                                                                          \
    RENORM_COMMON                                                            \
    const int EnP_ = dpp_shr1_i(En_);                                        \
    E = dead ? EnP_ : En_;                                                   \
    const int Ep_ = dpp_shr1_i(E);                                           \
    const int d_ = Ep_ - E;                                                  \
    int dc_ = d_ < -126 ? -126 : (d_ > 126 ? 126 : d_);                      \
    fac = (d_ < -126) ? 0.0f : __int_as_float((unsigned)(dc_ + 127) << 23);  \
  }

#define RENORMB                                                              \
  {                                                                          \
    RENORM_COMMON                                                            \
    const int EnP_ = dpp_shl1_i(En_);                                        \
    E = dead ? EnP_ : En_;                                                   \
    const int Ep_ = dpp_shl1_i(E);                                           \
    const int d_ = Ep_ - E;                                                  \
    int dc_ = d_ < -126 ? -126 : (d_ > 126 ? 126 : d_);                      \
    fac = (d_ < -126) ? 0.0f : __int_as_float((unsigned)(dc_ + 127) << 23);  \
  }

  // prologue: chunks 0..5 into buffers 0..5 (Ntot >= 109 >> 12)
  LOADC(0, CHK(0)); LOADC(1, CHK(1)); LOADC(2, CHK(2));
  LOADC(3, CHK(3)); LOADC(4, CHK(4)); LOADC(5, CHK(5));
  int i = 0;

  if (!dirb) {
    // first group (straight-line), then 6-chunk straight-line main loop
    STEP8F(0); LOADC(0, CHK(6));  RENORMF;
    STEP8F(1); LOADC(1, CHK(7));  RENORMF;
    STEP8F(2); LOADC(2, CHK(8));  RENORMF;
    STEP8F(3); LOADC(3, CHK(9));  RENORMF;
    STEP8F(4); LOADC(4, CHK(10)); RENORMF;
    STEP8F(5); LOADC(5, CHK(11)); RENORMF;
    i = 6;
    while (i + 12 <= Ntot) {
      STEP8F(0); LOADC(0, CHK(i + 6));  RENORMF;
      STEP8F(1); LOADC(1, CHK(i + 7));  RENORMF;
      STEP8F(2); LOADC(2, CHK(i + 8));  RENORMF;
      STEP8F(3); LOADC(3, CHK(i + 9));  RENORMF;
      STEP8F(4); LOADC(4, CHK(i + 10)); RENORMF;
      STEP8F(5); LOADC(5, CHK(i + 11)); RENORMF;
      i += 6;
    }
    const int r2 = Ntot - i;  // in [6,12)
    for (int k = 0; k < r2; ++k) {
      const int nx = i + k + 6;
      const bool pf = nx < Ntot;
      switch (k % 6) {
        case 0: STEP8F(0); RENORMF; if (pf) LOADC(0, CHK(nx)); break;
        case 1: STEP8F(1); RENORMF; if (pf) LOADC(1, CHK(nx)); break;
        case 2: STEP8F(2); RENORMF; if (pf) LOADC(2, CHK(nx)); break;
        case 3: STEP8F(3); RENORMF; if (pf) LOADC(3, CHK(nx)); break;
        case 4: STEP8F(4); RENORMF; if (pf) LOADC(4, CHK(nx)); break;
        default: STEP8F(5); RENORMF; if (pf) LOADC(5, CHK(nx)); break;
      }
    }
    *(float4*)(AF + b * 512 + lane * 8) = make_float4(a0, a1, a2, a3);
    *(float4*)(AF + b * 512 + lane * 8 + 4) = make_float4(a4, a5, a6, a7);
    EF[b * 64 + lane] = E;
  } else {
    const int uh0 = rem ? (rem - 1) : 7;  // masked tail is the first consumed chunk
    STEP8B(0, uh0); LOADC(0, CHK(6));  RENORMB;
    STEP8B(1, 7);   LOADC(1, CHK(7));  RENORMB;
    STEP8B(2, 7);   LOADC(2, CHK(8));  RENORMB;
    STEP8B(3, 7);   LOADC(3, CHK(9));  RENORMB;
    STEP8B(4, 7);   LOADC(4, CHK(10)); RENORMB;
    STEP8B(5, 7);   LOADC(5, CHK(11)); RENORMB;
    i = 6;
    while (i + 12 <= Ntot) {
      STEP8B(0, 7); LOADC(0, CHK(i + 6));  RENORMB;
      STEP8B(1, 7); LOADC(1, CHK(i + 7));  RENORMB;
      STEP8B(2, 7); LOADC(2, CHK(i + 8));  RENORMB;
      STEP8B(3, 7); LOADC(3, CHK(i + 9));  RENORMB;
      STEP8B(4, 7); LOADC(4, CHK(i + 10)); RENORMB;
      STEP8B(5, 7); LOADC(5, CHK(i + 11)); RENORMB;
      i += 6;
    }
    const int r2 = Ntot - i;  // in [6,12)
    for (int k = 0; k < r2; ++k) {
      const int nx = i + k + 6;
      const bool pf = nx < Ntot;
      switch (k % 6) {
        case 0: STEP8B(0, 7); RENORMB; if (pf) LOADC(0, CHK(nx)); break;
        case 1: STEP8B(1, 7); RENORMB; if (pf) LOADC(1, CHK(nx)); break;
        case 2: STEP8B(2, 7); RENORMB; if (pf) LOADC(2, CHK(nx)); break;
        case 3: STEP8B(3, 7); RENORMB; if (pf) LOADC(3, CHK(nx)); break;
        case 4: STEP8B(4, 7); RENORMB; if (pf) LOADC(4, CHK(nx)); break;
        default: STEP8B(5, 7); RENORMB; if (pf) LOADC(5, CHK(nx)); break;
      }
    }
    // delta = one emission-less backward step of gamma_{8Cf}
    const float sa = dpp_shl1_f(a0) * fac;
    const float sb = dpp_shl1_f(a1) * fac;
    const float d0 = a0 + a1;
    const float d1 = fmaf(m1, a3, a1 + a2);
    const float d2 = a2 + a3;
    const float d3 = fmaf(m2, a5, a3 + a4);
    const float d4 = a4 + a5;
    const float d5 = fmaf(m3, a7, a5 + a6);
    const float d6 = a6 + a7;
    const float d7 = fmaf(m0n, sb, a7 + sa);
    *(float4*)(DD + b * 512 + lane * 8) = make_float4(d0, d1, d2, d3);
    *(float4*)(DD + b * 512 + lane * 8 + 4) = make_float4(d4, d5, d6, d7);
    EB[b * 64 + lane] = E;
  }
#undef LOADC
#undef STEP8F
#undef STEP8B
#undef RENORM_COMMON
#undef RENORMF
#undef RENORMB
#undef CHK
}

// ---- splice + final sum: out = -sum_b log( sum_s alpha[s]*delta[s] ) + len*ln(32) ----
__global__ __launch_bounds__(512) void kcomb(const int* __restrict__ lens,
                                             const float* __restrict__ AF,
                                             const int* __restrict__ EF,
                                             const float* __restrict__ DD,
                                             const int* __restrict__ EB,
                                             float* __restrict__ out) {
  const int wid = threadIdx.x >> 6;
  const int lane = threadIdx.x & 63;
  __shared__ float part[8];
  float acc = 0.0f;
#pragma unroll
  for (int q = 0; q < 8; ++q) {
    const int b = wid * 8 + q;
    const float4 f0 = *(const float4*)(AF + b * 512 + lane * 8);
    const float4 f1 = *(const float4*)(AF + b * 512 + lane * 8 + 4);
    const float4 g0 = *(const float4*)(DD + b * 512 + lane * 8);
    const float4 g1 = *(const float4*)(DD + b * 512 + lane * 8 + 4);
    const float dot = ((f0.x * g0.x + f0.y * g0.y) + (f0.z * g0.z + f0.w * g0.w)) +
                      ((f1.x * g1.x + f1.y * g1.y) + (f1.z * g1.z + f1.w * g1.w));
    const int Es = EF[b * 64 + lane] + EB[b * 64 + lane];
    const bool z = (dot == 0.0f);
    int Ek = z ? (-(1 << 28)) : Es;
#pragma unroll
    for (int off = 32; off; off >>= 1) {
      const int o = __shfl_xor(Ek, off);
      Ek = o > Ek ? o : Ek;
    }
    float v = z ? 0.0f : ldexpf(dot, Es - Ek);
#pragma unroll
    for (int off = 32; off; off >>= 1) v += __shfl_xor(v, off);
    const float ll = __logf(v) + (float)Ek * 0.69314718056f - (float)lens[b] * 3.46573590280f;
    acc -= ll;
  }
  if (lane == 0) part[wid] = acc;
  __syncthreads();
  if (threadIdx.x == 0) {
    float s = ((part[0] + part[1]) + (part[2] + part[3])) +
              ((part[4] + part[5]) + (part[6] + part[7]));
    out[0] = s;
  }
}

extern "C" void kernel_launch(void* const* d_in, const int* in_sizes, int n_in,
                              void* d_out, int out_size, void* d_ws, size_t ws_size,
                              hipStream_t stream) {
  const float* logits = (const float*)d_in[0];     // [B,T,V] fp32 — read-only
  const int* input_lengths = (const int*)d_in[1];  // [B]
  const int* targets = (const int*)d_in[2];        // [B,L]
  float* out = (float*)d_out;                      // [1]
  // ws layout (bytes): compact fp16 pairs [B][250][4][64] x16B = 65,536,000;
  // blank f32 [B][2048] = 524,288; (gap); AF/EF/DD/EB.
  u64x2* cull2 = (u64x2*)d_ws;
  float* bl = (float*)((char*)d_ws + 65536000);
  float* AF = (float*)((char*)d_ws + 66125824);
  int* EF = (int*)((char*)d_ws + 66256896);
  float* DD = (float*)((char*)d_ws + 66273280);
  int* EB = (int*)((char*)d_ws + 66404352);
  (void)in_sizes; (void)n_in; (void)out_size; (void)ws_size;

  kprob<<<B_ * NJB, 256, 0, stream>>>(logits, input_lengths, targets, cull2, bl);
  krec<<<2 * B_, 64, 0, stream>>>(input_lengths, targets, cull2, bl, AF, EF, DD, EB);
  kcomb<<<1, 512, 0, stream>>>(input_lengths, AF, EF, DD, EB, out);
}